// Round 2
// baseline (1161.681 us; speedup 1.0000x reference)
//
#include <hip/hip_runtime.h>
#include <hip/hip_bf16.h>

constexpr int INC_ = 96;
constexpr int D_   = 192;
constexpr int DI_  = 384;

// workspace offsets in floats
constexpr size_t O_T1   = 0;                      // 8192*96
constexpr size_t O_T2   = O_T1 + (size_t)8192*96; // 8192*192
constexpr size_t O_XZ   = O_T2 + (size_t)8192*192;// 8192*768
constexpr size_t O_XC   = O_XZ + (size_t)8192*768;// 8192*384
constexpr size_t O_DBL  = O_XC + (size_t)8192*384;// 8192*44
constexpr size_t O_DT   = O_DBL+ (size_t)8192*44; // 8192*384
constexpr size_t O_YF   = O_DT + (size_t)8192*384;// 8192*384
constexpr size_t O_U    = O_YF + (size_t)8192*384;// 8192*192
constexpr size_t O_V    = O_U  + (size_t)8192*192;// 8*192*1024

// ---------------- conv3x3 (INC->INC) + BN + exact GELU, writes (b,l,c) ----------------
__global__ __launch_bounds__(256) void conv1_k(
    const float* __restrict__ x, const float* __restrict__ w1,
    const float* __restrict__ g, const float* __restrict__ b,
    const float* __restrict__ m, const float* __restrict__ v,
    float* __restrict__ t1)
{
    const int n  = blockIdx.x / INC_;
    const int co = blockIdx.x % INC_;
    const int tid = threadIdx.x;
    const int p0 = tid << 2;
    const int h = p0 >> 5, w0 = p0 & 31;
    float acc0 = 0.f, acc1 = 0.f, acc2 = 0.f, acc3 = 0.f;
    const float* wbase = w1 + (size_t)co * INC_ * 9;
    const float* xbase = x + (size_t)n * INC_ * 1024;
    for (int ci = 0; ci < INC_; ++ci) {
        const float* xp = xbase + ci * 1024;
        const float* wp = wbase + ci * 9;
        #pragma unroll
        for (int kh = 0; kh < 3; ++kh) {
            int ih = h - 1 + kh;
            if ((unsigned)ih >= 32u) continue;
            float wf0 = wp[kh*3 + 0];
            float wf1 = wp[kh*3 + 1];
            float wf2 = wp[kh*3 + 2];
            float in6[6];
            #pragma unroll
            for (int jj = 0; jj < 6; ++jj) {
                int iw = w0 - 1 + jj;
                in6[jj] = ((unsigned)iw < 32u) ? xp[ih*32 + iw] : 0.f;
            }
            acc0 += in6[0]*wf0 + in6[1]*wf1 + in6[2]*wf2;
            acc1 += in6[1]*wf0 + in6[2]*wf1 + in6[3]*wf2;
            acc2 += in6[2]*wf0 + in6[3]*wf1 + in6[4]*wf2;
            acc3 += in6[3]*wf0 + in6[4]*wf1 + in6[5]*wf2;
        }
    }
    float sc = g[co] * rsqrtf(v[co] + 1e-5f);
    float bb = b[co] - m[co] * sc;
    float accs[4] = {acc0, acc1, acc2, acc3};
    #pragma unroll
    for (int jj = 0; jj < 4; ++jj) {
        float xv = accs[jj] * sc + bb;
        float gel = 0.5f * xv * (1.f + erff(xv * 0.70710678f));
        t1[(size_t)(n*1024 + p0 + jj) * INC_ + co] = gel;
    }
}

// ---------------- generic tiled GEMM: C[M,N] = A[M,K] @ B[N,K]^T ----------------
enum { EPI_NONE = 0, EPI_BN_SILU = 1, EPI_SP = 2 };

template<int EPI, int NCHW>
__global__ __launch_bounds__(256) void gemm_k(
    int M, int N, int K, int lda,
    const float* __restrict__ A, const float* __restrict__ B, float* __restrict__ C,
    const float* __restrict__ p0, const float* __restrict__ p1,
    const float* __restrict__ p2, const float* __restrict__ p3)
{
    __shared__ float As[16][68];
    __shared__ float Bs[16][68];
    const int tid = threadIdx.x;
    const int tx = tid & 15, ty = tid >> 4;
    const int rowBase = blockIdx.x * 64;
    const int colBase = blockIdx.y * 64;
    const int lr = tid >> 2;
    const int kq = (tid & 3) << 2;
    float acc[4][4] = {};
    for (int kt = 0; kt < K; kt += 16) {
        float4 av = make_float4(0.f, 0.f, 0.f, 0.f);
        float4 bv = make_float4(0.f, 0.f, 0.f, 0.f);
        if (kt + kq < K)
            av = *(const float4*)(A + (size_t)(rowBase + lr) * lda + kt + kq);
        int bn = colBase + lr;
        if (bn < N && kt + kq < K)
            bv = *(const float4*)(B + (size_t)bn * K + kt + kq);
        As[kq+0][lr] = av.x; As[kq+1][lr] = av.y; As[kq+2][lr] = av.z; As[kq+3][lr] = av.w;
        Bs[kq+0][lr] = bv.x; Bs[kq+1][lr] = bv.y; Bs[kq+2][lr] = bv.z; Bs[kq+3][lr] = bv.w;
        __syncthreads();
        #pragma unroll
        for (int kk = 0; kk < 16; ++kk) {
            float4 a = *(const float4*)&As[kk][ty << 2];
            float4 b = *(const float4*)&Bs[kk][tx << 2];
            float ar[4] = {a.x, a.y, a.z, a.w};
            float br[4] = {b.x, b.y, b.z, b.w};
            #pragma unroll
            for (int i = 0; i < 4; ++i)
                #pragma unroll
                for (int jj = 0; jj < 4; ++jj)
                    acc[i][jj] += ar[i] * br[jj];
        }
        __syncthreads();
    }
    #pragma unroll
    for (int jj = 0; jj < 4; ++jj) {
        int col = colBase + (tx << 2) + jj;
        if (col >= N) continue;
        float sc = 0.f, bb = 0.f;
        if (EPI == EPI_BN_SILU) {
            sc = p0[col] * rsqrtf(p3[col] + 1e-5f);
            bb = p1[col] - p2[col] * sc;
        } else if (EPI == EPI_SP) {
            bb = p0[col];
        }
        #pragma unroll
        for (int i = 0; i < 4; ++i) {
            int row = rowBase + (ty << 2) + i;
            float xv = acc[i][jj];
            if (EPI == EPI_BN_SILU) {
                xv = xv * sc + bb;
                xv = xv / (1.f + __expf(-xv));
            } else if (EPI == EPI_SP) {
                xv += bb;
                xv = (xv > 20.f) ? xv : log1pf(__expf(xv));
            }
            size_t idx;
            if (NCHW) idx = ((size_t)((row >> 10) * D_ + col) << 10) | (size_t)(row & 1023);
            else      idx = (size_t)row * N + col;
            C[idx] = xv;
        }
    }
}

// ---------------- depthwise causal conv (K=4) + SiLU ----------------
__global__ __launch_bounds__(256) void dwconv_k(
    const float* __restrict__ xz, const float* __restrict__ cw, const float* __restrict__ cb,
    float* __restrict__ xc)
{
    int idx = blockIdx.x * 256 + threadIdx.x;   // 8*1024*384 total
    int c = idx % DI_;
    int bl = idx / DI_;
    int l = bl & 1023;
    float acc = cb[c];
    #pragma unroll
    for (int k = 0; k < 4; ++k) {
        int ll = l - 3 + k;
        if (ll >= 0) acc += xz[(size_t)(bl - 3 + k) * 768 + c] * cw[c*4 + k];
    }
    xc[(size_t)bl * DI_ + c] = acc / (1.f + __expf(-acc));
}

// ---------------- selective scan: block per (b,d), chunked parallel scan ----------------
__global__ __launch_bounds__(256) void scan_k(
    const float* __restrict__ dt, const float* __restrict__ dbl,
    const float* __restrict__ xc, const float* __restrict__ xz,
    const float* __restrict__ A_log, const float* __restrict__ Dp,
    float* __restrict__ yf)
{
    const int bd = blockIdx.x;
    const int b = bd / DI_, d = bd % DI_;
    const int tid = threadIdx.x;
    const int j = tid >> 4, n = tid & 15;
    const float And = -__expf(A_log[d*16 + n]);
    __shared__ float Ap[16][16], Hl[16][16], Ci[16][17];
    const int r0 = b * 1024 + j * 64;
    float h = 0.f, ap = 1.f;
    for (int i = 0; i < 64; ++i) {
        int r = r0 + i;
        float dtv = dt[(size_t)r * DI_ + d];
        float xcv = xc[(size_t)r * DI_ + d];
        float bs  = dbl[(size_t)r * 44 + 12 + n];
        float a = __expf(dtv * And);
        h = a * h + dtv * bs * xcv;
        ap *= a;
    }
    Ap[j][n] = ap; Hl[j][n] = h;
    __syncthreads();
    if (tid < 16) {
        float c = 0.f;
        #pragma unroll
        for (int jj = 0; jj < 16; ++jj) {
            Ci[jj][tid] = c;
            c = Ap[jj][tid] * c + Hl[jj][tid];
        }
    }
    __syncthreads();
    h = Ci[j][n];
    const float dp = Dp[d];
    for (int i = 0; i < 64; ++i) {
        int r = r0 + i;
        float dtv = dt[(size_t)r * DI_ + d];
        float xcv = xc[(size_t)r * DI_ + d];
        float bs  = dbl[(size_t)r * 44 + 12 + n];
        float cs  = dbl[(size_t)r * 44 + 28 + n];
        h = __expf(dtv * And) * h + dtv * bs * xcv;
        float yv = h * cs;
        yv += __shfl_xor(yv, 1);
        yv += __shfl_xor(yv, 2);
        yv += __shfl_xor(yv, 4);
        yv += __shfl_xor(yv, 8);
        if (n == 0) {
            float zv = xz[(size_t)r * 768 + 384 + d];
            float o = (yv + xcv * dp) * (zv / (1.f + __expf(-zv)));
            yf[(size_t)r * DI_ + d] = o;
        }
    }
}

// ---------------- conv3x3 (D->D) + BN + exact GELU, NCHW in/out, f32 out ----------------
__global__ __launch_bounds__(256) void conv4_k(
    const float* __restrict__ vin, const float* __restrict__ w4,
    const float* __restrict__ g, const float* __restrict__ b,
    const float* __restrict__ m, const float* __restrict__ vv,
    float* __restrict__ out)
{
    const int n  = blockIdx.x / D_;
    const int co = blockIdx.x % D_;
    const int tid = threadIdx.x;
    const int p0 = tid << 2;
    const int h = p0 >> 5, w0 = p0 & 31;
    float acc0 = 0.f, acc1 = 0.f, acc2 = 0.f, acc3 = 0.f;
    const float* wbase = w4 + (size_t)co * D_ * 9;
    const float* xbase = vin + (size_t)n * D_ * 1024;
    for (int ci = 0; ci < D_; ++ci) {
        const float* xp = xbase + ci * 1024;
        const float* wp = wbase + ci * 9;
        #pragma unroll
        for (int kh = 0; kh < 3; ++kh) {
            int ih = h - 1 + kh;
            if ((unsigned)ih >= 32u) continue;
            float wf0 = wp[kh*3 + 0];
            float wf1 = wp[kh*3 + 1];
            float wf2 = wp[kh*3 + 2];
            float in6[6];
            #pragma unroll
            for (int jj = 0; jj < 6; ++jj) {
                int iw = w0 - 1 + jj;
                in6[jj] = ((unsigned)iw < 32u) ? xp[ih*32 + iw] : 0.f;
            }
            acc0 += in6[0]*wf0 + in6[1]*wf1 + in6[2]*wf2;
            acc1 += in6[1]*wf0 + in6[2]*wf1 + in6[3]*wf2;
            acc2 += in6[2]*wf0 + in6[3]*wf1 + in6[4]*wf2;
            acc3 += in6[3]*wf0 + in6[4]*wf1 + in6[5]*wf2;
        }
    }
    float sc = g[co] * rsqrtf(vv[co] + 1e-5f);
    float bb = b[co] - m[co] * sc;
    float accs[4] = {acc0, acc1, acc2, acc3};
    #pragma unroll
    for (int jj = 0; jj < 4; ++jj) {
        float xv = accs[jj] * sc + bb;
        float gel = 0.5f * xv * (1.f + erff(xv * 0.70710678f));
        out[((size_t)n * D_ + co) * 1024 + p0 + jj] = gel;
    }
}

extern "C" void kernel_launch(void* const* d_in, const int* in_sizes, int n_in,
                              void* d_out, int out_size, void* d_ws, size_t ws_size,
                              hipStream_t stream) {
    const float* x     = (const float*)d_in[0];
    const float* w1    = (const float*)d_in[1];
    const float* g1    = (const float*)d_in[2];
    const float* b1    = (const float*)d_in[3];
    const float* m1    = (const float*)d_in[4];
    const float* v1    = (const float*)d_in[5];
    const float* w2    = (const float*)d_in[6];
    const float* g2    = (const float*)d_in[7];
    const float* b2    = (const float*)d_in[8];
    const float* m2    = (const float*)d_in[9];
    const float* v2    = (const float*)d_in[10];
    const float* in_w  = (const float*)d_in[11];
    const float* cw    = (const float*)d_in[12];
    const float* cb    = (const float*)d_in[13];
    const float* xp_w  = (const float*)d_in[14];
    const float* dt_w  = (const float*)d_in[15];
    const float* dt_b  = (const float*)d_in[16];
    const float* A_log = (const float*)d_in[17];
    const float* Dp    = (const float*)d_in[18];
    const float* out_w = (const float*)d_in[19];
    const float* w3    = (const float*)d_in[20];
    const float* g3    = (const float*)d_in[21];
    const float* b3    = (const float*)d_in[22];
    const float* m3    = (const float*)d_in[23];
    const float* v3    = (const float*)d_in[24];
    const float* w4    = (const float*)d_in[25];
    const float* g4    = (const float*)d_in[26];
    const float* b4    = (const float*)d_in[27];
    const float* m4    = (const float*)d_in[28];
    const float* v4    = (const float*)d_in[29];

    float* ws  = (float*)d_ws;
    float* t1  = ws + O_T1;
    float* t2  = ws + O_T2;
    float* xzb = ws + O_XZ;
    float* xcb = ws + O_XC;
    float* dbl = ws + O_DBL;
    float* dtb = ws + O_DT;
    float* yfb = ws + O_YF;
    float* ub  = ws + O_U;
    float* vb  = ws + O_V;

    // 1) conv3x3 96->96 + BN + GELU  -> t1 (b,l,96)
    conv1_k<<<8 * INC_, 256, 0, stream>>>(x, w1, g1, b1, m1, v1, t1);

    // 2) 1x1 conv 96->192 + BN + SiLU -> t2 (8192,192)
    gemm_k<EPI_BN_SILU, 0><<<dim3(128, 3), 256, 0, stream>>>(
        8192, 192, 96, 96, t1, w2, t2, g2, b2, m2, v2);

    // 3) in-proj: xz = t2 @ in_w^T  (8192,768)
    gemm_k<EPI_NONE, 0><<<dim3(128, 12), 256, 0, stream>>>(
        8192, 768, 192, 192, t2, in_w, xzb, nullptr, nullptr, nullptr, nullptr);

    // 4) depthwise causal conv + SiLU -> xc (8192,384)
    dwconv_k<<<12288, 256, 0, stream>>>(xzb, cw, cb, xcb);

    // 5) x-proj: dbl = xc @ xp_w^T (8192,44)
    gemm_k<EPI_NONE, 0><<<dim3(128, 1), 256, 0, stream>>>(
        8192, 44, 384, 384, xcb, xp_w, dbl, nullptr, nullptr, nullptr, nullptr);

    // 6) dt = softplus(dbl[:, :12] @ dt_w^T + dt_b) (8192,384)
    gemm_k<EPI_SP, 0><<<dim3(128, 6), 256, 0, stream>>>(
        8192, 384, 12, 44, dbl, dt_w, dtb, dt_b, nullptr, nullptr, nullptr);

    // 7) selective scan + gate -> yf (8192,384)
    scan_k<<<8 * DI_, 256, 0, stream>>>(dtb, dbl, xcb, xzb, A_log, Dp, yfb);

    // 8) out-proj: u = yf @ out_w^T (8192,192)
    gemm_k<EPI_NONE, 0><<<dim3(128, 3), 256, 0, stream>>>(
        8192, 192, 384, 384, yfb, out_w, ub, nullptr, nullptr, nullptr, nullptr);

    // 9) 1x1 conv 192->192 + BN + SiLU -> v (NCHW)
    gemm_k<EPI_BN_SILU, 1><<<dim3(128, 3), 256, 0, stream>>>(
        8192, 192, 192, 192, ub, w3, vb, g3, b3, m3, v3);

    // 10) conv3x3 192->192 + BN + GELU -> out (f32 NCHW)
    conv4_k<<<8 * D_, 256, 0, stream>>>(vb, w4, g4, b4, m4, v4, (float*)d_out);
}

// Round 3
// 682.255 us; speedup vs baseline: 1.7027x; 1.7027x over previous
//
#include <hip/hip_runtime.h>
#include <hip/hip_bf16.h>

constexpr int INC_ = 96;
constexpr int D_   = 192;
constexpr int DI_  = 384;

// workspace offsets in floats
constexpr size_t O_T1   = 0;                      // 8192*96
constexpr size_t O_T2   = O_T1 + (size_t)8192*96; // 8192*192
constexpr size_t O_XZ   = O_T2 + (size_t)8192*192;// 8192*768
constexpr size_t O_XC   = O_XZ + (size_t)8192*768;// 8192*384
constexpr size_t O_DBL  = O_XC + (size_t)8192*384;// 8192*44
constexpr size_t O_DT   = O_DBL+ (size_t)8192*44; // 8192*384
constexpr size_t O_YF   = O_DT + (size_t)8192*384;// 8192*384
constexpr size_t O_U    = O_YF + (size_t)8192*384;// 8192*192
constexpr size_t O_V    = O_U  + (size_t)8192*192;// 8*192*1024

// ---------------- LDS-tiled 3x3 conv + BN + exact GELU ----------------
// Block: 8 rows x 32 cols (256 px, 1 px/thread) of one image, G output chans.
// Input channels staged CI_T at a time as zero-padded 10x34 LDS tiles.
// Weights are wave-uniform -> SGPR loads; VALU does only FMAs.
// OUT_BLC=1: store (b,l,c) via 2 float4 (requires G==8). else NCHW scalar.
template<int CIN, int COUT, int G, int OUT_BLC>
__global__ __launch_bounds__(256) void conv3x3_k(
    const float* __restrict__ xin, const float* __restrict__ wgt,
    const float* __restrict__ g, const float* __restrict__ b,
    const float* __restrict__ m, const float* __restrict__ v,
    float* __restrict__ out)
{
    constexpr int CI_T = 16;
    __shared__ float smem[CI_T][10][34];
    const int tid = threadIdx.x;
    const int q = blockIdx.x;          // row quarter 0..3
    const int coBase = blockIdx.y * G; // output channel group
    const int n = blockIdx.z;          // image
    const int r0 = q * 8;
    const int prow = tid >> 5;         // 0..7
    const int col  = tid & 31;         // 0..31

    // zero entire tile once (borders + out-of-image rows stay zero)
    {
        float* sflat = &smem[0][0][0];
        for (int i = tid; i < CI_T * 10 * 34; i += 256) sflat[i] = 0.f;
    }

    float acc[G];
    #pragma unroll
    for (int i = 0; i < G; ++i) acc[i] = 0.f;

    for (int ciBase = 0; ciBase < CIN; ciBase += CI_T) {
        __syncthreads();   // previous compute (or zeroing) done
        // stage: 160 (ci,row) pairs, one row of 32 floats each
        if (tid < CI_T * 10) {
            const int ci = tid / 10;
            const int row = tid % 10;
            const int grow = r0 - 1 + row;
            if ((unsigned)grow < 32u) {
                const float4* src = (const float4*)(xin +
                    (((size_t)n * CIN + ciBase + ci) << 10) + (grow << 5));
                float4 vv[8];
                #pragma unroll
                for (int j = 0; j < 8; ++j) vv[j] = src[j];
                #pragma unroll
                for (int j = 0; j < 8; ++j) {
                    smem[ci][row][1 + 4*j + 0] = vv[j].x;
                    smem[ci][row][1 + 4*j + 1] = vv[j].y;
                    smem[ci][row][1 + 4*j + 2] = vv[j].z;
                    smem[ci][row][1 + 4*j + 3] = vv[j].w;
                }
            }
        }
        __syncthreads();
        // compute
        for (int ci = 0; ci < CI_T; ++ci) {
            float in9[9];
            #pragma unroll
            for (int dr = 0; dr < 3; ++dr)
                #pragma unroll
                for (int dc = 0; dc < 3; ++dc)
                    in9[dr*3 + dc] = smem[ci][prow + dr][col + dc];
            #pragma unroll
            for (int cc = 0; cc < G; ++cc) {
                const float* wp = wgt + ((size_t)(coBase + cc) * CIN + ciBase + ci) * 9;
                float a = acc[cc];
                #pragma unroll
                for (int t = 0; t < 9; ++t) a += in9[t] * wp[t];
                acc[cc] = a;
            }
        }
    }

    const int px = r0 * 32 + prow * 32 + col;  // pixel index within image
    if (OUT_BLC) {
        // (b,l,c) layout: this thread owns 8 contiguous channels at its pixel
        float o[G];
        #pragma unroll
        for (int cc = 0; cc < G; ++cc) {
            const int co = coBase + cc;
            float sc = g[co] * rsqrtf(v[co] + 1e-5f);
            float bb = b[co] - m[co] * sc;
            float xv = acc[cc] * sc + bb;
            o[cc] = 0.5f * xv * (1.f + erff(xv * 0.70710678f));
        }
        float* dst = out + (size_t)(n * 1024 + px) * COUT + coBase;
        #pragma unroll
        for (int jj = 0; jj < G / 4; ++jj)
            ((float4*)dst)[jj] = make_float4(o[4*jj], o[4*jj+1], o[4*jj+2], o[4*jj+3]);
    } else {
        #pragma unroll
        for (int cc = 0; cc < G; ++cc) {
            const int co = coBase + cc;
            float sc = g[co] * rsqrtf(v[co] + 1e-5f);
            float bb = b[co] - m[co] * sc;
            float xv = acc[cc] * sc + bb;
            float gel = 0.5f * xv * (1.f + erff(xv * 0.70710678f));
            out[(((size_t)n * COUT + co) << 10) + px] = gel;
        }
    }
}

// ---------------- generic tiled GEMM: C[M,N] = A[M,K] @ B[N,K]^T ----------------
enum { EPI_NONE = 0, EPI_BN_SILU = 1, EPI_SP = 2 };

template<int EPI, int NCHW>
__global__ __launch_bounds__(256) void gemm_k(
    int M, int N, int K, int lda,
    const float* __restrict__ A, const float* __restrict__ B, float* __restrict__ C,
    const float* __restrict__ p0, const float* __restrict__ p1,
    const float* __restrict__ p2, const float* __restrict__ p3)
{
    __shared__ float As[16][68];
    __shared__ float Bs[16][68];
    const int tid = threadIdx.x;
    const int tx = tid & 15, ty = tid >> 4;
    const int rowBase = blockIdx.x * 64;
    const int colBase = blockIdx.y * 64;
    const int lr = tid >> 2;
    const int kq = (tid & 3) << 2;
    float acc[4][4] = {};
    for (int kt = 0; kt < K; kt += 16) {
        float4 av = make_float4(0.f, 0.f, 0.f, 0.f);
        float4 bv = make_float4(0.f, 0.f, 0.f, 0.f);
        if (kt + kq < K)
            av = *(const float4*)(A + (size_t)(rowBase + lr) * lda + kt + kq);
        int bn = colBase + lr;
        if (bn < N && kt + kq < K)
            bv = *(const float4*)(B + (size_t)bn * K + kt + kq);
        As[kq+0][lr] = av.x; As[kq+1][lr] = av.y; As[kq+2][lr] = av.z; As[kq+3][lr] = av.w;
        Bs[kq+0][lr] = bv.x; Bs[kq+1][lr] = bv.y; Bs[kq+2][lr] = bv.z; Bs[kq+3][lr] = bv.w;
        __syncthreads();
        #pragma unroll
        for (int kk = 0; kk < 16; ++kk) {
            float4 a = *(const float4*)&As[kk][ty << 2];
            float4 b = *(const float4*)&Bs[kk][tx << 2];
            float ar[4] = {a.x, a.y, a.z, a.w};
            float br[4] = {b.x, b.y, b.z, b.w};
            #pragma unroll
            for (int i = 0; i < 4; ++i)
                #pragma unroll
                for (int jj = 0; jj < 4; ++jj)
                    acc[i][jj] += ar[i] * br[jj];
        }
        __syncthreads();
    }
    #pragma unroll
    for (int jj = 0; jj < 4; ++jj) {
        int col = colBase + (tx << 2) + jj;
        if (col >= N) continue;
        float sc = 0.f, bb = 0.f;
        if (EPI == EPI_BN_SILU) {
            sc = p0[col] * rsqrtf(p3[col] + 1e-5f);
            bb = p1[col] - p2[col] * sc;
        } else if (EPI == EPI_SP) {
            bb = p0[col];
        }
        #pragma unroll
        for (int i = 0; i < 4; ++i) {
            int row = rowBase + (ty << 2) + i;
            float xv = acc[i][jj];
            if (EPI == EPI_BN_SILU) {
                xv = xv * sc + bb;
                xv = xv / (1.f + __expf(-xv));
            } else if (EPI == EPI_SP) {
                xv += bb;
                xv = (xv > 20.f) ? xv : log1pf(__expf(xv));
            }
            size_t idx;
            if (NCHW) idx = ((size_t)((row >> 10) * D_ + col) << 10) | (size_t)(row & 1023);
            else      idx = (size_t)row * N + col;
            C[idx] = xv;
        }
    }
}

// ---------------- depthwise causal conv (K=4) + SiLU ----------------
__global__ __launch_bounds__(256) void dwconv_k(
    const float* __restrict__ xz, const float* __restrict__ cw, const float* __restrict__ cb,
    float* __restrict__ xc)
{
    int idx = blockIdx.x * 256 + threadIdx.x;   // 8*1024*384 total
    int c = idx % DI_;
    int bl = idx / DI_;
    int l = bl & 1023;
    float acc = cb[c];
    #pragma unroll
    for (int k = 0; k < 4; ++k) {
        int ll = l - 3 + k;
        if (ll >= 0) acc += xz[(size_t)(bl - 3 + k) * 768 + c] * cw[c*4 + k];
    }
    xc[(size_t)bl * DI_ + c] = acc / (1.f + __expf(-acc));
}

// ---------------- selective scan: block per (b,d), chunked parallel scan ----------------
__global__ __launch_bounds__(256) void scan_k(
    const float* __restrict__ dt, const float* __restrict__ dbl,
    const float* __restrict__ xc, const float* __restrict__ xz,
    const float* __restrict__ A_log, const float* __restrict__ Dp,
    float* __restrict__ yf)
{
    const int bd = blockIdx.x;
    const int b = bd / DI_, d = bd % DI_;
    const int tid = threadIdx.x;
    const int j = tid >> 4, n = tid & 15;
    const float And = -__expf(A_log[d*16 + n]);
    __shared__ float Ap[16][16], Hl[16][16], Ci[16][17];
    const int r0 = b * 1024 + j * 64;
    float h = 0.f, ap = 1.f;
    for (int i = 0; i < 64; ++i) {
        int r = r0 + i;
        float dtv = dt[(size_t)r * DI_ + d];
        float xcv = xc[(size_t)r * DI_ + d];
        float bs  = dbl[(size_t)r * 44 + 12 + n];
        float a = __expf(dtv * And);
        h = a * h + dtv * bs * xcv;
        ap *= a;
    }
    Ap[j][n] = ap; Hl[j][n] = h;
    __syncthreads();
    if (tid < 16) {
        float c = 0.f;
        #pragma unroll
        for (int jj = 0; jj < 16; ++jj) {
            Ci[jj][tid] = c;
            c = Ap[jj][tid] * c + Hl[jj][tid];
        }
    }
    __syncthreads();
    h = Ci[j][n];
    const float dp = Dp[d];
    for (int i = 0; i < 64; ++i) {
        int r = r0 + i;
        float dtv = dt[(size_t)r * DI_ + d];
        float xcv = xc[(size_t)r * DI_ + d];
        float bs  = dbl[(size_t)r * 44 + 12 + n];
        float cs  = dbl[(size_t)r * 44 + 28 + n];
        h = __expf(dtv * And) * h + dtv * bs * xcv;
        float yv = h * cs;
        yv += __shfl_xor(yv, 1);
        yv += __shfl_xor(yv, 2);
        yv += __shfl_xor(yv, 4);
        yv += __shfl_xor(yv, 8);
        if (n == 0) {
            float zv = xz[(size_t)r * 768 + 384 + d];
            float o = (yv + xcv * dp) * (zv / (1.f + __expf(-zv)));
            yf[(size_t)r * DI_ + d] = o;
        }
    }
}

extern "C" void kernel_launch(void* const* d_in, const int* in_sizes, int n_in,
                              void* d_out, int out_size, void* d_ws, size_t ws_size,
                              hipStream_t stream) {
    const float* x     = (const float*)d_in[0];
    const float* w1    = (const float*)d_in[1];
    const float* g1    = (const float*)d_in[2];
    const float* b1    = (const float*)d_in[3];
    const float* m1    = (const float*)d_in[4];
    const float* v1    = (const float*)d_in[5];
    const float* w2    = (const float*)d_in[6];
    const float* g2    = (const float*)d_in[7];
    const float* b2    = (const float*)d_in[8];
    const float* m2    = (const float*)d_in[9];
    const float* v2    = (const float*)d_in[10];
    const float* in_w  = (const float*)d_in[11];
    const float* cw    = (const float*)d_in[12];
    const float* cb    = (const float*)d_in[13];
    const float* xp_w  = (const float*)d_in[14];
    const float* dt_w  = (const float*)d_in[15];
    const float* dt_b  = (const float*)d_in[16];
    const float* A_log = (const float*)d_in[17];
    const float* Dp    = (const float*)d_in[18];
    const float* out_w = (const float*)d_in[19];
    const float* w3    = (const float*)d_in[20];
    const float* g3    = (const float*)d_in[21];
    const float* b3    = (const float*)d_in[22];
    const float* m3    = (const float*)d_in[23];
    const float* v3    = (const float*)d_in[24];
    const float* w4    = (const float*)d_in[25];
    const float* g4    = (const float*)d_in[26];
    const float* b4    = (const float*)d_in[27];
    const float* m4    = (const float*)d_in[28];
    const float* v4    = (const float*)d_in[29];

    float* ws  = (float*)d_ws;
    float* t1  = ws + O_T1;
    float* t2  = ws + O_T2;
    float* xzb = ws + O_XZ;
    float* xcb = ws + O_XC;
    float* dbl = ws + O_DBL;
    float* dtb = ws + O_DT;
    float* yfb = ws + O_YF;
    float* ub  = ws + O_U;
    float* vb  = ws + O_V;

    // 1) conv3x3 96->96 + BN + GELU -> t1 (b,l,96); G=8, out (b,l,c)
    conv3x3_k<96, 96, 8, 1><<<dim3(4, 12, 8), 256, 0, stream>>>(
        x, w1, g1, b1, m1, v1, t1);

    // 2) 1x1 conv 96->192 + BN + SiLU -> t2 (8192,192)
    gemm_k<EPI_BN_SILU, 0><<<dim3(128, 3), 256, 0, stream>>>(
        8192, 192, 96, 96, t1, w2, t2, g2, b2, m2, v2);

    // 3) in-proj: xz = t2 @ in_w^T  (8192,768)
    gemm_k<EPI_NONE, 0><<<dim3(128, 12), 256, 0, stream>>>(
        8192, 768, 192, 192, t2, in_w, xzb, nullptr, nullptr, nullptr, nullptr);

    // 4) depthwise causal conv + SiLU -> xc (8192,384)
    dwconv_k<<<12288, 256, 0, stream>>>(xzb, cw, cb, xcb);

    // 5) x-proj: dbl = xc @ xp_w^T (8192,44)
    gemm_k<EPI_NONE, 0><<<dim3(128, 1), 256, 0, stream>>>(
        8192, 44, 384, 384, xcb, xp_w, dbl, nullptr, nullptr, nullptr, nullptr);

    // 6) dt = softplus(dbl[:, :12] @ dt_w^T + dt_b) (8192,384)
    gemm_k<EPI_SP, 0><<<dim3(128, 6), 256, 0, stream>>>(
        8192, 384, 12, 44, dbl, dt_w, dtb, dt_b, nullptr, nullptr, nullptr);

    // 7) selective scan + gate -> yf (8192,384)
    scan_k<<<8 * DI_, 256, 0, stream>>>(dtb, dbl, xcb, xzb, A_log, Dp, yfb);

    // 8) out-proj: u = yf @ out_w^T (8192,192)
    gemm_k<EPI_NONE, 0><<<dim3(128, 3), 256, 0, stream>>>(
        8192, 192, 384, 384, yfb, out_w, ub, nullptr, nullptr, nullptr, nullptr);

    // 9) 1x1 conv 192->192 + BN + SiLU -> v (NCHW)
    gemm_k<EPI_BN_SILU, 1><<<dim3(128, 3), 256, 0, stream>>>(
        8192, 192, 192, 192, ub, w3, vb, g3, b3, m3, v3);

    // 10) conv3x3 192->192 + BN + GELU -> out (f32 NCHW); G=16
    conv3x3_k<192, 192, 16, 0><<<dim3(4, 12, 8), 256, 0, stream>>>(
        vb, w4, g4, b4, m4, v4, (float*)d_out);
}

// Round 4
// 486.759 us; speedup vs baseline: 2.3866x; 1.4016x over previous
//
#include <hip/hip_runtime.h>
#include <hip/hip_bf16.h>

using u16 = unsigned short;
using short8 = __attribute__((ext_vector_type(8))) short;
using f32x4  = __attribute__((ext_vector_type(4))) float;

constexpr int INC_ = 96;
constexpr int D_   = 192;
constexpr int DI_  = 384;

// workspace offsets in floats
constexpr size_t O_T1   = 0;                      // 8192*96
constexpr size_t O_T2   = O_T1 + (size_t)8192*96; // 8192*192
constexpr size_t O_XZ   = O_T2 + (size_t)8192*192;// 8192*768
constexpr size_t O_XC   = O_XZ + (size_t)8192*768;// 8192*384
constexpr size_t O_DBL  = O_XC + (size_t)8192*384;// 8192*44
constexpr size_t O_DT   = O_DBL+ (size_t)8192*44; // 8192*384
constexpr size_t O_YF   = O_DT + (size_t)8192*384;// 8192*384
constexpr size_t O_U    = O_YF + (size_t)8192*384;// 8192*192
constexpr size_t O_V    = O_U  + (size_t)8192*192;// bf16 arena (8192*192 floats)

__device__ __forceinline__ u16 f2b(float f) {
    __hip_bfloat16 h = __float2bfloat16(f);
    return *reinterpret_cast<u16*>(&h);
}

// ---------------- weight transform: [CO][CI][3][3] f32 -> [9][CO][CI] bf16 ----------------
__global__ __launch_bounds__(256) void cvt_w_k(
    const float* __restrict__ src, u16* __restrict__ dst, int CO, int CI)
{
    int total = 9 * CO * CI;
    for (int idx = blockIdx.x * 256 + threadIdx.x; idx < total; idx += gridDim.x * 256) {
        int ci = idx % CI;
        int rem = idx / CI;
        int co = rem % CO;
        int t = rem / CO;
        dst[idx] = f2b(src[((size_t)co * CI + ci) * 9 + t]);
    }
}

// ---------------- x: NCHW f32 -> NHWC bf16 ----------------
__global__ __launch_bounds__(256) void cvt_x_k(
    const float* __restrict__ src, u16* __restrict__ dst)
{
    int idx = blockIdx.x * 256 + threadIdx.x;   // 8192*96
    int ci = idx % 96;
    int px = idx / 96;
    dst[idx] = f2b(src[(((size_t)(px >> 10) * 96 + ci) << 10) | (size_t)(px & 1023)]);
}

// ---------------- 3x3 conv as bf16-MFMA shift-GEMM + BN + exact GELU ----------------
// Xb: [8192][CIN] bf16 NHWC. Wt: [9][COUT][CIN] bf16.
// OUTM 0: f32 NHWC (out[px*COUT+co]); OUTM 1: f32 NCHW (out[(img*COUT+co)*1024+off]).
template<int CIN, int COUT, int NTILE, int OUTM>
__global__ __launch_bounds__(256) void conv3x3_mfma_k(
    const u16* __restrict__ Xb, const u16* __restrict__ Wt,
    const float* __restrict__ g, const float* __restrict__ b,
    const float* __restrict__ m, const float* __restrict__ v,
    float* __restrict__ out)
{
    constexpr int LDA = 40;             // padded row stride (bf16) -> conflict-free b128 reads
    constexpr int NT = NTILE / 16;
    __shared__ u16 As[64 * LDA];
    __shared__ u16 Bs[NTILE * LDA];
    const int tid = threadIdx.x;
    const int wave = tid >> 6, lane = tid & 63;
    const int quad = lane >> 4, l16 = lane & 15;
    const int rowBase = blockIdx.x * 64;       // 64 rows, single image (1024%64==0)
    const int colBase = blockIdx.y * NTILE;

    f32x4 acc[NT];
    #pragma unroll
    for (int nt = 0; nt < NT; ++nt)
        #pragma unroll
        for (int i = 0; i < 4; ++i) acc[nt][i] = 0.f;

    const int ar = tid >> 2, aseg = tid & 3;   // A staging: 64 rows x 4 segs
    const int apx = rowBase + ar;
    const int ah = (apx >> 5) & 31, aw = apx & 31;

    for (int t = 0; t < 9; ++t) {
        const int dr = t / 3 - 1, dc = t % 3 - 1;
        const bool avalid = ((unsigned)(ah + dr) < 32u) && ((unsigned)(aw + dc) < 32u);
        const int apxs = apx + dr * 32 + dc;
        for (int ci0 = 0; ci0 < CIN; ci0 += 32) {
            __syncthreads();
            // stage A (64 x 32, one uint4 per thread)
            uint4 va = make_uint4(0u, 0u, 0u, 0u);
            if (avalid)
                va = *(const uint4*)(Xb + (size_t)apxs * CIN + ci0 + aseg * 8);
            *(uint4*)(As + ar * LDA + aseg * 8) = va;
            // stage B (NTILE x 32)
            if (tid < NTILE * 4) {
                int r = tid >> 2, seg = tid & 3;
                uint4 vb = *(const uint4*)(Wt + ((size_t)t * COUT + colBase + r) * CIN + ci0 + seg * 8);
                *(uint4*)(Bs + r * LDA + seg * 8) = vb;
            }
            __syncthreads();
            short8 a = *(const short8*)(As + (wave * 16 + l16) * LDA + quad * 8);
            #pragma unroll
            for (int nt = 0; nt < NT; ++nt) {
                short8 bf = *(const short8*)(Bs + (nt * 16 + l16) * LDA + quad * 8);
                acc[nt] = __builtin_amdgcn_mfma_f32_16x16x32_bf16(a, bf, acc[nt], 0, 0, 0);
            }
        }
    }

    // epilogue: D[row=quad*4+reg][col=l16] ; rows are px, cols are co
    const int px0 = rowBase + wave * 16 + quad * 4;
    #pragma unroll
    for (int nt = 0; nt < NT; ++nt) {
        const int co = colBase + nt * 16 + l16;
        const float sc = g[co] * rsqrtf(v[co] + 1e-5f);
        const float bb = b[co] - m[co] * sc;
        float o[4];
        #pragma unroll
        for (int r = 0; r < 4; ++r) {
            float xv = acc[nt][r] * sc + bb;
            o[r] = 0.5f * xv * (1.f + erff(xv * 0.70710678f));
        }
        if (OUTM == 0) {
            #pragma unroll
            for (int r = 0; r < 4; ++r)
                out[(size_t)(px0 + r) * COUT + co] = o[r];
        } else {
            const int img = px0 >> 10, off = px0 & 1023;
            *(float4*)(out + (((size_t)img * COUT + co) << 10) + off) =
                make_float4(o[0], o[1], o[2], o[3]);
        }
    }
}

// ---------------- generic tiled f32 GEMM: C[M,N] = A[M,K] @ B[N,K]^T ----------------
enum { EPI_NONE = 0, EPI_BN_SILU = 1, EPI_SP = 2 };
// OUTM 0: f32 row-major; 2: bf16 row-major

template<int EPI, int OUTM>
__global__ __launch_bounds__(256) void gemm_k(
    int M, int N, int K, int lda,
    const float* __restrict__ A, const float* __restrict__ B, void* __restrict__ C,
    const float* __restrict__ p0, const float* __restrict__ p1,
    const float* __restrict__ p2, const float* __restrict__ p3)
{
    __shared__ float As[16][68];
    __shared__ float Bs[16][68];
    const int tid = threadIdx.x;
    const int tx = tid & 15, ty = tid >> 4;
    const int rowBase = blockIdx.x * 64;
    const int colBase = blockIdx.y * 64;
    const int lr = tid >> 2;
    const int kq = (tid & 3) << 2;
    float acc[4][4] = {};
    for (int kt = 0; kt < K; kt += 16) {
        float4 av = make_float4(0.f, 0.f, 0.f, 0.f);
        float4 bv = make_float4(0.f, 0.f, 0.f, 0.f);
        if (kt + kq < K)
            av = *(const float4*)(A + (size_t)(rowBase + lr) * lda + kt + kq);
        int bn = colBase + lr;
        if (bn < N && kt + kq < K)
            bv = *(const float4*)(B + (size_t)bn * K + kt + kq);
        As[kq+0][lr] = av.x; As[kq+1][lr] = av.y; As[kq+2][lr] = av.z; As[kq+3][lr] = av.w;
        Bs[kq+0][lr] = bv.x; Bs[kq+1][lr] = bv.y; Bs[kq+2][lr] = bv.z; Bs[kq+3][lr] = bv.w;
        __syncthreads();
        #pragma unroll
        for (int kk = 0; kk < 16; ++kk) {
            float4 a = *(const float4*)&As[kk][ty << 2];
            float4 b = *(const float4*)&Bs[kk][tx << 2];
            float ar[4] = {a.x, a.y, a.z, a.w};
            float br[4] = {b.x, b.y, b.z, b.w};
            #pragma unroll
            for (int i = 0; i < 4; ++i)
                #pragma unroll
                for (int jj = 0; jj < 4; ++jj)
                    acc[i][jj] += ar[i] * br[jj];
        }
        __syncthreads();
    }
    #pragma unroll
    for (int jj = 0; jj < 4; ++jj) {
        int col = colBase + (tx << 2) + jj;
        if (col >= N) continue;
        float sc = 0.f, bb = 0.f;
        if (EPI == EPI_BN_SILU) {
            sc = p0[col] * rsqrtf(p3[col] + 1e-5f);
            bb = p1[col] - p2[col] * sc;
        } else if (EPI == EPI_SP) {
            bb = p0[col];
        }
        #pragma unroll
        for (int i = 0; i < 4; ++i) {
            int row = rowBase + (ty << 2) + i;
            float xv = acc[i][jj];
            if (EPI == EPI_BN_SILU) {
                xv = xv * sc + bb;
                xv = xv / (1.f + __expf(-xv));
            } else if (EPI == EPI_SP) {
                xv += bb;
                xv = (xv > 20.f) ? xv : log1pf(__expf(xv));
            }
            size_t idx = (size_t)row * N + col;
            if (OUTM == 2) ((u16*)C)[idx] = f2b(xv);
            else           ((float*)C)[idx] = xv;
        }
    }
}

// ---------------- depthwise causal conv (K=4) + SiLU ----------------
__global__ __launch_bounds__(256) void dwconv_k(
    const float* __restrict__ xz, const float* __restrict__ cw, const float* __restrict__ cb,
    float* __restrict__ xc)
{
    int idx = blockIdx.x * 256 + threadIdx.x;   // 8*1024*384 total
    int c = idx % DI_;
    int bl = idx / DI_;
    int l = bl & 1023;
    float acc = cb[c];
    #pragma unroll
    for (int k = 0; k < 4; ++k) {
        int ll = l - 3 + k;
        if (ll >= 0) acc += xz[(size_t)(bl - 3 + k) * 768 + c] * cw[c*4 + k];
    }
    xc[(size_t)bl * DI_ + c] = acc / (1.f + __expf(-acc));
}

// ---------------- selective scan: block per (b,d), chunked parallel scan ----------------
__global__ __launch_bounds__(256) void scan_k(
    const float* __restrict__ dt, const float* __restrict__ dbl,
    const float* __restrict__ xc, const float* __restrict__ xz,
    const float* __restrict__ A_log, const float* __restrict__ Dp,
    float* __restrict__ yf)
{
    const int bd = blockIdx.x;
    const int b = bd / DI_, d = bd % DI_;
    const int tid = threadIdx.x;
    const int j = tid >> 4, n = tid & 15;
    const float And = -__expf(A_log[d*16 + n]);
    __shared__ float Ap[16][16], Hl[16][16], Ci[16][17];
    const int r0 = b * 1024 + j * 64;
    float h = 0.f, ap = 1.f;
    for (int i = 0; i < 64; ++i) {
        int r = r0 + i;
        float dtv = dt[(size_t)r * DI_ + d];
        float xcv = xc[(size_t)r * DI_ + d];
        float bs  = dbl[(size_t)r * 44 + 12 + n];
        float a = __expf(dtv * And);
        h = a * h + dtv * bs * xcv;
        ap *= a;
    }
    Ap[j][n] = ap; Hl[j][n] = h;
    __syncthreads();
    if (tid < 16) {
        float c = 0.f;
        #pragma unroll
        for (int jj = 0; jj < 16; ++jj) {
            Ci[jj][tid] = c;
            c = Ap[jj][tid] * c + Hl[jj][tid];
        }
    }
    __syncthreads();
    h = Ci[j][n];
    const float dp = Dp[d];
    for (int i = 0; i < 64; ++i) {
        int r = r0 + i;
        float dtv = dt[(size_t)r * DI_ + d];
        float xcv = xc[(size_t)r * DI_ + d];
        float bs  = dbl[(size_t)r * 44 + 12 + n];
        float cs  = dbl[(size_t)r * 44 + 28 + n];
        h = __expf(dtv * And) * h + dtv * bs * xcv;
        float yv = h * cs;
        yv += __shfl_xor(yv, 1);
        yv += __shfl_xor(yv, 2);
        yv += __shfl_xor(yv, 4);
        yv += __shfl_xor(yv, 8);
        if (n == 0) {
            float zv = xz[(size_t)r * 768 + 384 + d];
            float o = (yv + xcv * dp) * (zv / (1.f + __expf(-zv)));
            yf[(size_t)r * DI_ + d] = o;
        }
    }
}

extern "C" void kernel_launch(void* const* d_in, const int* in_sizes, int n_in,
                              void* d_out, int out_size, void* d_ws, size_t ws_size,
                              hipStream_t stream) {
    const float* x     = (const float*)d_in[0];
    const float* w1    = (const float*)d_in[1];
    const float* g1    = (const float*)d_in[2];
    const float* b1    = (const float*)d_in[3];
    const float* m1    = (const float*)d_in[4];
    const float* v1    = (const float*)d_in[5];
    const float* w2    = (const float*)d_in[6];
    const float* g2    = (const float*)d_in[7];
    const float* b2    = (const float*)d_in[8];
    const float* m2    = (const float*)d_in[9];
    const float* v2    = (const float*)d_in[10];
    const float* in_w  = (const float*)d_in[11];
    const float* cw    = (const float*)d_in[12];
    const float* cb    = (const float*)d_in[13];
    const float* xp_w  = (const float*)d_in[14];
    const float* dt_w  = (const float*)d_in[15];
    const float* dt_b  = (const float*)d_in[16];
    const float* A_log = (const float*)d_in[17];
    const float* Dp    = (const float*)d_in[18];
    const float* out_w = (const float*)d_in[19];
    const float* w3    = (const float*)d_in[20];
    const float* g3    = (const float*)d_in[21];
    const float* b3    = (const float*)d_in[22];
    const float* m3    = (const float*)d_in[23];
    const float* v3    = (const float*)d_in[24];
    const float* w4    = (const float*)d_in[25];
    const float* g4    = (const float*)d_in[26];
    const float* b4    = (const float*)d_in[27];
    const float* m4    = (const float*)d_in[28];
    const float* v4    = (const float*)d_in[29];

    float* ws  = (float*)d_ws;
    float* t1  = ws + O_T1;
    float* t2  = ws + O_T2;
    float* xzb = ws + O_XZ;
    float* xcb = ws + O_XC;
    float* dbl = ws + O_DBL;
    float* dtb = ws + O_DT;
    float* yfb = ws + O_YF;
    float* ub  = ws + O_U;
    // bf16 arena in the old O_V region (6.29 MB available, 5.55 MB used)
    u16* Xb4 = (u16*)(ws + O_V);
    u16* Xb1 = Xb4 + (size_t)8192 * 192;
    u16* wt1 = Xb1 + (size_t)8192 * 96;
    u16* wt4 = wt1 + (size_t)9 * 96 * 96;

    // 0) converters
    cvt_w_k<<<64, 256, 0, stream>>>(w1, wt1, 96, 96);
    cvt_w_k<<<192, 256, 0, stream>>>(w4, wt4, 192, 192);
    cvt_x_k<<<3072, 256, 0, stream>>>(x, Xb1);

    // 1) conv3x3 96->96 + BN + GELU (bf16 MFMA) -> t1 f32 NHWC
    conv3x3_mfma_k<96, 96, 32, 0><<<dim3(128, 3), 256, 0, stream>>>(
        Xb1, wt1, g1, b1, m1, v1, t1);

    // 2) 1x1 conv 96->192 + BN + SiLU -> t2 (8192,192)
    gemm_k<EPI_BN_SILU, 0><<<dim3(128, 3), 256, 0, stream>>>(
        8192, 192, 96, 96, t1, w2, t2, g2, b2, m2, v2);

    // 3) in-proj: xz = t2 @ in_w^T  (8192,768)
    gemm_k<EPI_NONE, 0><<<dim3(128, 12), 256, 0, stream>>>(
        8192, 768, 192, 192, t2, in_w, xzb, nullptr, nullptr, nullptr, nullptr);

    // 4) depthwise causal conv + SiLU -> xc (8192,384)
    dwconv_k<<<12288, 256, 0, stream>>>(xzb, cw, cb, xcb);

    // 5) x-proj: dbl = xc @ xp_w^T (8192,44)
    gemm_k<EPI_NONE, 0><<<dim3(128, 1), 256, 0, stream>>>(
        8192, 44, 384, 384, xcb, xp_w, dbl, nullptr, nullptr, nullptr, nullptr);

    // 6) dt = softplus(dbl[:, :12] @ dt_w^T + dt_b) (8192,384)
    gemm_k<EPI_SP, 0><<<dim3(128, 6), 256, 0, stream>>>(
        8192, 384, 12, 44, dbl, dt_w, dtb, dt_b, nullptr, nullptr, nullptr);

    // 7) selective scan + gate -> yf (8192,384)
    scan_k<<<8 * DI_, 256, 0, stream>>>(dtb, dbl, xcb, xzb, A_log, Dp, yfb);

    // 8) out-proj: u = yf @ out_w^T (8192,192)
    gemm_k<EPI_NONE, 0><<<dim3(128, 3), 256, 0, stream>>>(
        8192, 192, 384, 384, yfb, out_w, ub, nullptr, nullptr, nullptr, nullptr);

    // 9) 1x1 conv 192->192 + BN + SiLU -> Xb4 bf16 NHWC
    gemm_k<EPI_BN_SILU, 2><<<dim3(128, 3), 256, 0, stream>>>(
        8192, 192, 192, 192, ub, w3, Xb4, g3, b3, m3, v3);

    // 10) conv3x3 192->192 + BN + GELU (bf16 MFMA) -> out f32 NCHW
    conv3x3_mfma_k<192, 192, 64, 1><<<dim3(128, 3), 256, 0, stream>>>(
        Xb4, wt4, g4, b4, m4, v4, (float*)d_out);
}